// Round 2
// baseline (949.562 us; speedup 1.0000x reference)
//
#include <hip/hip_runtime.h>
#include <hip/hip_bf16.h>

// ---------------- problem constants ----------------
#define N_NODES 50000
#define N_EDGES 800000
#define TOT_E   (N_EDGES + N_NODES)   // with self loops
#define IN_F    38
#define HIDC    64
#define NH      4
#define F1      256                    // NH*HIDC
#define F2      128                    // OUT
#define NGRAPH  128
#define NEG_SLOPE 0.2f
#define EPS_A   1e-16f

typedef __hip_bfloat16 bf16;

// ---------------- ws layout (bytes, 256-aligned) ----------------
// flag | converted params (f32) | xl1,xr1,h (bf16 N*256) | xl2,xr2 (bf16 N*128)
// | cnt | offs | cursor | csr | psum | pcnt
constexpr size_t al256(size_t x) { return (x + 255) & ~(size_t)255; }

// converted-params element offsets (f32 elements)
#define P_WL1   0
#define P_BL1   (P_WL1 + IN_F * F1)        // 9728
#define P_WR1   (P_BL1 + F1)               // 9984
#define P_BR1   (P_WR1 + IN_F * F1)        // 19712
#define P_ATT1  (P_BR1 + F1)               // 19968
#define P_BIAS1 (P_ATT1 + F1)              // 20224
#define P_WL2   (P_BIAS1 + F1)             // 20480
#define P_BL2   (P_WL2 + F1 * F2)          // 53248
#define P_WR2   (P_BL2 + F2)               // 53376
#define P_BR2   (P_WR2 + F1 * F2)          // 86144
#define P_ATT2  (P_BR2 + F2)               // 86272
#define P_BIAS2 (P_ATT2 + F2)              // 86400
#define P_TOTAL (P_BIAS2 + F2)             // 86528

constexpr size_t OFF_FLAG = 0;
constexpr size_t OFF_PAR  = 256;
constexpr size_t OFF_XL1  = OFF_PAR + al256((size_t)P_TOTAL * 4);
constexpr size_t OFF_XR1  = OFF_XL1 + al256((size_t)N_NODES * F1 * 2);
constexpr size_t OFF_H    = OFF_XR1 + al256((size_t)N_NODES * F1 * 2);
constexpr size_t OFF_XL2  = OFF_H   + al256((size_t)N_NODES * F1 * 2);
constexpr size_t OFF_XR2  = OFF_XL2 + al256((size_t)N_NODES * F2 * 2);
constexpr size_t OFF_CNT  = OFF_XR2 + al256((size_t)N_NODES * F2 * 2);
constexpr size_t OFF_OFFS = OFF_CNT + al256((size_t)N_NODES * 4);
constexpr size_t OFF_CUR  = OFF_OFFS+ al256((size_t)(N_NODES + 1) * 4);
constexpr size_t OFF_CSR  = OFF_CUR + al256((size_t)(N_NODES + 1) * 4);
constexpr size_t OFF_PSUM = OFF_CSR + al256((size_t)TOT_E * 4);
constexpr size_t OFF_PCNT = OFF_PSUM+ al256((size_t)NGRAPH * F2 * 4);

// ---------------- dtype detection ----------------
// Interpret first 64 halfwords of x as bf16. Genuine bf16 N(0,1) data has
// exponents near 127; an f32 buffer misread as bf16 has ~half its halfwords
// with random exponent bits. flag: 1 = inputs are f32, 0 = inputs are bf16.
__global__ void detect_k(const void* __restrict__ x, int* __restrict__ flag) {
  const int lane = threadIdx.x;
  const unsigned short* u = (const unsigned short*)x;
  unsigned short b = u[lane];
  int e = (b >> 7) & 0xFF;
  int insane = !((e == 0) || (e >= 96 && e <= 158));
#pragma unroll
  for (int off = 32; off > 0; off >>= 1) insane += __shfl_xor(insane, off, 64);
  if (lane == 0) *flag = (insane > 8) ? 1 : 0;
}

// ---------------- param conversion (either dtype -> f32 scratch) ----------------
struct CvtArgs {
  const void* src[12];
  int n[12];
  int dstoff[12];
};

__global__ void convert_k(CvtArgs a, const int* __restrict__ flag,
                          float* __restrict__ dst) {
  const int row = blockIdx.y;
  const int i = blockIdx.x * 256 + threadIdx.x;
  if (i >= a.n[row]) return;
  float v;
  if (*flag) {
    v = ((const float*)a.src[row])[i];
  } else {
    v = (float)((const bf16*)a.src[row])[i];
  }
  dst[a.dstoff[row] + i] = v;
}

// ---------------- GEMM 1: x(N,38) -> xl1,xr1 (N,256), bf16 out ----------------
__global__ __launch_bounds__(256) void gemm1_k(
    const int* __restrict__ flag, const void* __restrict__ x,
    const float* __restrict__ par,
    bf16* __restrict__ xl1, bf16* __restrict__ xr1) {
  __shared__ float xs[16][IN_F + 2];
  const int t = threadIdx.x;
  const int node0 = blockIdx.x * 16;
  const int isf = *flag;
  const float* xf = (const float*)x;
  const bf16*  xb = (const bf16*)x;
  for (int i = t; i < 16 * IN_F; i += 256) {
    int n = i / IN_F, k = i - n * IN_F;
    int node = node0 + n;
    float v = 0.f;
    if (node < N_NODES) {
      int idx = node * IN_F + k;
      if (isf) v = xf[idx]; else v = (float)xb[idx];
    }
    xs[n][k] = v;
  }
  __syncthreads();
  const float* Wl = par + P_WL1;
  const float* Wr = par + P_WR1;
  float accl[16], accr[16];
#pragma unroll
  for (int n = 0; n < 16; n++) { accl[n] = 0.f; accr[n] = 0.f; }
#pragma unroll 2
  for (int k = 0; k < IN_F; k++) {
    float wl = Wl[k * F1 + t];
    float wr = Wr[k * F1 + t];
#pragma unroll
    for (int n = 0; n < 16; n++) {
      float xv = xs[n][k];
      accl[n] += xv * wl;
      accr[n] += xv * wr;
    }
  }
  float bL = par[P_BL1 + t], bR = par[P_BR1 + t];
  for (int n = 0; n < 16; n++) {
    int node = node0 + n;
    if (node >= N_NODES) break;
    xl1[(size_t)node * F1 + t] = (bf16)(accl[n] + bL);
    xr1[(size_t)node * F1 + t] = (bf16)(accr[n] + bR);
  }
}

// ---------------- GEMM 2: h(N,256) -> xl2,xr2 (N,128) ----------------
__global__ __launch_bounds__(128) void gemm2_k(
    const bf16* __restrict__ h, const float* __restrict__ par,
    bf16* __restrict__ xl2, bf16* __restrict__ xr2) {
  __shared__ float hs[16][F1];   // 16 KB
  const int t = threadIdx.x;
  const int node0 = blockIdx.x * 16;
  for (int i = t; i < 16 * F1; i += 128) {
    int n = i >> 8, k = i & 255;
    int node = node0 + n;
    hs[n][k] = (node < N_NODES) ? (float)h[(size_t)node * F1 + k] : 0.f;
  }
  __syncthreads();
  const float* Wl = par + P_WL2;
  const float* Wr = par + P_WR2;
  float accl[16], accr[16];
#pragma unroll
  for (int n = 0; n < 16; n++) { accl[n] = 0.f; accr[n] = 0.f; }
#pragma unroll 4
  for (int k = 0; k < F1; k++) {
    float wl = Wl[k * F2 + t];
    float wr = Wr[k * F2 + t];
#pragma unroll
    for (int n = 0; n < 16; n++) {
      float hv = hs[n][k];
      accl[n] += hv * wl;
      accr[n] += hv * wr;
    }
  }
  float bL = par[P_BL2 + t], bR = par[P_BR2 + t];
  for (int n = 0; n < 16; n++) {
    int node = node0 + n;
    if (node >= N_NODES) break;
    xl2[(size_t)node * F2 + t] = (bf16)(accl[n] + bL);
    xr2[(size_t)node * F2 + t] = (bf16)(accr[n] + bR);
  }
}

// ---------------- CSR build ----------------
__global__ void count_k(const int* __restrict__ ei, int* __restrict__ cnt) {
  int e = blockIdx.x * 256 + threadIdx.x;
  if (e >= TOT_E) return;
  int dst = (e < N_EDGES) ? ei[N_EDGES + e] : (e - N_EDGES);
  atomicAdd(&cnt[dst], 1);
}

__global__ __launch_bounds__(1024) void scan_k(const int* __restrict__ cnt,
                                               int* __restrict__ offs,
                                               int* __restrict__ cursor) {
  __shared__ int wsum[16];
  __shared__ int carry_s;
  const int t = threadIdx.x;
  const int lane = t & 63, w = t >> 6;
  if (t == 0) carry_s = 0;
  __syncthreads();
  for (int base = 0; base < N_NODES; base += 1024) {
    int idx = base + t;
    int v = (idx < N_NODES) ? cnt[idx] : 0;
    int s = v;
#pragma unroll
    for (int off = 1; off < 64; off <<= 1) {
      int u = __shfl_up(s, off, 64);
      if (lane >= off) s += u;
    }
    if (lane == 63) wsum[w] = s;
    __syncthreads();
    int prefix = carry_s;
    for (int i = 0; i < w; i++) prefix += wsum[i];
    int excl = prefix + s - v;
    if (idx < N_NODES) { offs[idx] = excl; cursor[idx] = excl; }
    __syncthreads();
    if (t == 1023) carry_s = prefix + s;
    __syncthreads();
  }
  if (t == 0) offs[N_NODES] = carry_s;
}

__global__ void scatter_k(const int* __restrict__ ei, int* __restrict__ cursor,
                          int* __restrict__ csr) {
  int e = blockIdx.x * 256 + threadIdx.x;
  if (e >= TOT_E) return;
  int src, dst;
  if (e < N_EDGES) { src = ei[e]; dst = ei[N_EDGES + e]; }
  else             { src = dst = e - N_EDGES; }
  int pos = atomicAdd(&cursor[dst], 1);
  csr[pos] = src;
}

// ---------------- layer-1 aggregation: one block (4 waves = 4 heads) per dst ----------------
__global__ __launch_bounds__(256) void agg1_k(
    const bf16* __restrict__ xl1, const bf16* __restrict__ xr1,
    const float* __restrict__ par,
    const int* __restrict__ offs, const int* __restrict__ csr,
    bf16* __restrict__ hout) {
  const int dst = blockIdx.x;
  const int t = threadIdx.x;          // t = h*64 + c, wave == head
  float r = (float)xr1[(size_t)dst * F1 + t];
  float a = par[P_ATT1 + t];          // att (H,HID) row-major
  int e0 = offs[dst], e1 = offs[dst + 1];
  float m = -INFINITY, denom = 0.f, acc = 0.f;
  for (int i = e0; i < e1; i++) {
    int src = csr[i];
    float v = (float)xl1[(size_t)src * F1 + t];
    float s = v + r;
    s = (s > 0.f) ? s : NEG_SLOPE * s;
    float lt = s * a;
#pragma unroll
    for (int off = 32; off > 0; off >>= 1) lt += __shfl_xor(lt, off, 64);
    float mn = fmaxf(m, lt);
    float f = __expf(m - mn);          // exp(-inf)=0 on first edge
    float p = __expf(lt - mn);
    denom = denom * f + p;
    acc = acc * f + p * v;
    m = mn;
  }
  float o = acc / (denom + EPS_A) + par[P_BIAS1 + t];
  o = fmaxf(o, 0.f);
  hout[(size_t)dst * F1 + t] = (bf16)o;
}

// ---------------- layer-2 aggregation (1 head, C=128): one wave per dst ----------------
__global__ __launch_bounds__(64) void agg2_k(
    const bf16* __restrict__ xl2, const bf16* __restrict__ xr2,
    const float* __restrict__ par,
    const int* __restrict__ offs, const int* __restrict__ csr,
    const int* __restrict__ batch, float* __restrict__ poolsum) {
  const int dst = blockIdx.x;
  const int t = threadIdx.x;          // lane; handles c = 2t, 2t+1
  const int c0 = 2 * t, c1 = 2 * t + 1;
  float r0 = (float)xr2[(size_t)dst * F2 + c0];
  float r1 = (float)xr2[(size_t)dst * F2 + c1];
  float a0 = par[P_ATT2 + c0], a1 = par[P_ATT2 + c1];
  int e0 = offs[dst], e1 = offs[dst + 1];
  const __hip_bfloat162* __restrict__ xl2v = (const __hip_bfloat162*)xl2;
  float m = -INFINITY, denom = 0.f, acc0 = 0.f, acc1 = 0.f;
  for (int i = e0; i < e1; i++) {
    int src = csr[i];
    __hip_bfloat162 pv = xl2v[(size_t)src * (F2 / 2) + t];
    float v0 = (float)pv.x, v1 = (float)pv.y;
    float s0 = v0 + r0; s0 = (s0 > 0.f) ? s0 : NEG_SLOPE * s0;
    float s1 = v1 + r1; s1 = (s1 > 0.f) ? s1 : NEG_SLOPE * s1;
    float lt = s0 * a0 + s1 * a1;
#pragma unroll
    for (int off = 32; off > 0; off >>= 1) lt += __shfl_xor(lt, off, 64);
    float mn = fmaxf(m, lt);
    float f = __expf(m - mn);
    float p = __expf(lt - mn);
    denom = denom * f + p;
    acc0 = acc0 * f + p * v0;
    acc1 = acc1 * f + p * v1;
    m = mn;
  }
  float inv = 1.f / (denom + EPS_A);
  float o0 = fmaxf(acc0 * inv + par[P_BIAS2 + c0], 0.f);
  float o1 = fmaxf(acc1 * inv + par[P_BIAS2 + c1], 0.f);
  int g = batch[dst];
  atomicAdd(&poolsum[(size_t)g * F2 + c0], o0);
  atomicAdd(&poolsum[(size_t)g * F2 + c1], o1);
}

// ---------------- pooling count + finalize ----------------
__global__ void poolcnt_k(const int* __restrict__ batch, int* __restrict__ pc) {
  int n = blockIdx.x * 256 + threadIdx.x;
  if (n < N_NODES) atomicAdd(&pc[batch[n]], 1);
}

__global__ void final_k(const int* __restrict__ flag,
                        const float* __restrict__ psum, const int* __restrict__ pc,
                        void* __restrict__ out) {
  int i = blockIdx.x * 256 + threadIdx.x;
  if (i >= NGRAPH * F2) return;
  int g = i >> 7;
  float c = fmaxf((float)pc[g], 1.f);
  float v = psum[i] / c;
  if (*flag) ((float*)out)[i] = v;
  else       ((bf16*)out)[i] = (bf16)v;
}

// ---------------- launch ----------------
extern "C" void kernel_launch(void* const* d_in, const int* in_sizes, int n_in,
                              void* d_out, int out_size, void* d_ws, size_t ws_size,
                              hipStream_t stream) {
  (void)in_sizes; (void)n_in; (void)out_size; (void)ws_size;
  const void* x     = d_in[0];
  const int*  ei    = (const int*)d_in[1];
  const int*  batch = (const int*)d_in[2];

  char* ws = (char*)d_ws;
  int*   flag = (int*)(ws + OFF_FLAG);
  float* par  = (float*)(ws + OFF_PAR);
  bf16* xl1 = (bf16*)(ws + OFF_XL1);
  bf16* xr1 = (bf16*)(ws + OFF_XR1);
  bf16* h   = (bf16*)(ws + OFF_H);
  bf16* xl2 = (bf16*)(ws + OFF_XL2);
  bf16* xr2 = (bf16*)(ws + OFF_XR2);
  int* cnt    = (int*)(ws + OFF_CNT);
  int* offs   = (int*)(ws + OFF_OFFS);
  int* cursor = (int*)(ws + OFF_CUR);
  int* csr    = (int*)(ws + OFF_CSR);
  float* psum = (float*)(ws + OFF_PSUM);
  int* pcnt   = (int*)(ws + OFF_PCNT);

  hipMemsetAsync(cnt, 0, (size_t)N_NODES * 4, stream);
  hipMemsetAsync(psum, 0, (size_t)NGRAPH * F2 * 4, stream);
  hipMemsetAsync(pcnt, 0, (size_t)NGRAPH * 4, stream);

  detect_k<<<1, 64, 0, stream>>>(x, flag);

  CvtArgs ca;
  const int srcidx[12] = {3, 4, 5, 6, 7, 8, 9, 10, 11, 12, 13, 14};
  const int ns[12]     = {IN_F * F1, F1, IN_F * F1, F1, F1, F1,
                          F1 * F2, F2, F1 * F2, F2, F2, F2};
  const int doff[12]   = {P_WL1, P_BL1, P_WR1, P_BR1, P_ATT1, P_BIAS1,
                          P_WL2, P_BL2, P_WR2, P_BR2, P_ATT2, P_BIAS2};
  for (int i = 0; i < 12; i++) { ca.src[i] = d_in[srcidx[i]]; ca.n[i] = ns[i]; ca.dstoff[i] = doff[i]; }
  convert_k<<<dim3((F1 * F2 + 255) / 256, 12), 256, 0, stream>>>(ca, flag, par);

  const int nb16 = (N_NODES + 15) / 16;          // 3125
  const int ebl  = (TOT_E + 255) / 256;          // 3321

  gemm1_k<<<nb16, 256, 0, stream>>>(flag, x, par, xl1, xr1);
  count_k<<<ebl, 256, 0, stream>>>(ei, cnt);
  scan_k<<<1, 1024, 0, stream>>>(cnt, offs, cursor);
  scatter_k<<<ebl, 256, 0, stream>>>(ei, cursor, csr);
  agg1_k<<<N_NODES, 256, 0, stream>>>(xl1, xr1, par, offs, csr, h);
  gemm2_k<<<nb16, 128, 0, stream>>>(h, par, xl2, xr2);
  agg2_k<<<N_NODES, 64, 0, stream>>>(xl2, xr2, par, offs, csr, batch, psum);
  poolcnt_k<<<(N_NODES + 255) / 256, 256, 0, stream>>>(batch, pcnt);
  final_k<<<(NGRAPH * F2 + 255) / 256, 256, 0, stream>>>(flag, psum, pcnt, d_out);
}

// Round 3
// 774.174 us; speedup vs baseline: 1.2265x; 1.2265x over previous
//
#include <hip/hip_runtime.h>
#include <hip/hip_bf16.h>
#include <limits.h>

// ---------------- problem constants ----------------
#define N_NODES 50000
#define N_EDGES 800000
#define TOT_E   (N_EDGES + N_NODES)   // with self loops
#define IN_F    38
#define HIDC    64
#define NH      4
#define F1      256                    // NH*HIDC
#define F2      128                    // OUT
#define NGRAPH  128
#define NEG_SLOPE 0.2f
#define EPS_A   1e-16f

typedef __hip_bfloat16 bf16;

// ---------------- ws layout ----------------
constexpr size_t al256(size_t x) { return (x + 255) & ~(size_t)255; }

// converted-params element offsets (f32 elements)
#define P_WL1   0
#define P_BL1   (P_WL1 + IN_F * F1)
#define P_WR1   (P_BL1 + F1)
#define P_BR1   (P_WR1 + IN_F * F1)
#define P_ATT1  (P_BR1 + F1)
#define P_BIAS1 (P_ATT1 + F1)
#define P_WL2   (P_BIAS1 + F1)
#define P_BL2   (P_WL2 + F1 * F2)
#define P_WR2   (P_BL2 + F2)
#define P_BR2   (P_WR2 + F1 * F2)
#define P_ATT2  (P_BR2 + F2)
#define P_BIAS2 (P_ATT2 + F2)
#define P_TOTAL (P_BIAS2 + F2)

constexpr size_t OFF_FLAG = 0;
constexpr size_t OFF_PAR  = 256;
constexpr size_t OFF_XL1  = OFF_PAR + al256((size_t)P_TOTAL * 4);   // also reused as h2 later
constexpr size_t OFF_XR1  = OFF_XL1 + al256((size_t)N_NODES * F1 * 2);
constexpr size_t OFF_H    = OFF_XR1 + al256((size_t)N_NODES * F1 * 2);
constexpr size_t OFF_XL2  = OFF_H   + al256((size_t)N_NODES * F1 * 2);
constexpr size_t OFF_XR2  = OFF_XL2 + al256((size_t)N_NODES * F2 * 2);
constexpr size_t OFF_CNT  = OFF_XR2 + al256((size_t)N_NODES * F2 * 2);
constexpr size_t OFF_OFFS = OFF_CNT + al256((size_t)N_NODES * 4);
constexpr size_t OFF_CUR  = OFF_OFFS+ al256((size_t)(N_NODES + 1) * 4);
constexpr size_t OFF_CSR  = OFF_CUR + al256((size_t)(N_NODES + 1) * 4);
constexpr size_t OFF_GS   = OFF_CSR + al256((size_t)TOT_E * 4);
constexpr size_t OFF_GE   = OFF_GS  + al256((size_t)NGRAPH * 4);
constexpr size_t OFF_H2   = OFF_XL1;   // xl1 dead after agg1; reuse for h2 (N*F2 bf16)

// ---------------- helpers ----------------
__device__ __forceinline__ void load8bf(const bf16* __restrict__ p, float* f) {
  uint4 q = *(const uint4*)p;   // 16B = 8 bf16
  unsigned v[4] = {q.x, q.y, q.z, q.w};
#pragma unroll
  for (int i = 0; i < 4; i++) {
    f[2*i]   = __uint_as_float(v[i] << 16);
    f[2*i+1] = __uint_as_float(v[i] & 0xffff0000u);
  }
}

__device__ __forceinline__ float lrelu(float s) {
  return fmaxf(s, 0.f) + NEG_SLOPE * fminf(s, 0.f);
}

// ---------------- dtype detection (1 = f32 inputs, 0 = bf16) ----------------
__global__ void detect_k(const void* __restrict__ x, int* __restrict__ flag) {
  const int lane = threadIdx.x;
  const unsigned short* u = (const unsigned short*)x;
  unsigned short b = u[lane];
  int e = (b >> 7) & 0xFF;
  int insane = !((e == 0) || (e >= 96 && e <= 158));
#pragma unroll
  for (int off = 32; off > 0; off >>= 1) insane += __shfl_xor(insane, off, 64);
  if (lane == 0) *flag = (insane > 8) ? 1 : 0;
}

// ---------------- param conversion -> f32 scratch ----------------
struct CvtArgs { const void* src[12]; int n[12]; int dstoff[12]; };

__global__ void convert_k(CvtArgs a, const int* __restrict__ flag,
                          float* __restrict__ dst) {
  const int row = blockIdx.y;
  const int i = blockIdx.x * 256 + threadIdx.x;
  if (i >= a.n[row]) return;
  float v = (*flag) ? ((const float*)a.src[row])[i]
                    : (float)((const bf16*)a.src[row])[i];
  dst[a.dstoff[row] + i] = v;
}

// ---------------- GEMM 1: x(N,38) -> xl1,xr1 (N,256) bf16 ----------------
__global__ __launch_bounds__(256) void gemm1_k(
    const int* __restrict__ flag, const void* __restrict__ x,
    const float* __restrict__ par,
    bf16* __restrict__ xl1, bf16* __restrict__ xr1) {
  __shared__ float xs[16][IN_F + 2];
  const int t = threadIdx.x;
  const int node0 = blockIdx.x * 16;
  const int isf = *flag;
  const float* xf = (const float*)x;
  const bf16*  xb = (const bf16*)x;
  for (int i = t; i < 16 * IN_F; i += 256) {
    int n = i / IN_F, k = i - n * IN_F;
    int node = node0 + n;
    float v = 0.f;
    if (node < N_NODES) {
      int idx = node * IN_F + k;
      v = isf ? xf[idx] : (float)xb[idx];
    }
    xs[n][k] = v;
  }
  __syncthreads();
  const float* Wl = par + P_WL1;
  const float* Wr = par + P_WR1;
  float accl[16], accr[16];
#pragma unroll
  for (int n = 0; n < 16; n++) { accl[n] = 0.f; accr[n] = 0.f; }
#pragma unroll 2
  for (int k = 0; k < IN_F; k++) {
    float wl = Wl[k * F1 + t];
    float wr = Wr[k * F1 + t];
#pragma unroll
    for (int n = 0; n < 16; n++) {
      float xv = xs[n][k];
      accl[n] += xv * wl;
      accr[n] += xv * wr;
    }
  }
  float bL = par[P_BL1 + t], bR = par[P_BR1 + t];
  for (int n = 0; n < 16; n++) {
    int node = node0 + n;
    if (node >= N_NODES) break;
    xl1[(size_t)node * F1 + t] = (bf16)(accl[n] + bL);
    xr1[(size_t)node * F1 + t] = (bf16)(accr[n] + bR);
  }
}

// ---------------- GEMM 2: h(N,256) -> xl2,xr2 (N,128) ----------------
__global__ __launch_bounds__(128) void gemm2_k(
    const bf16* __restrict__ h, const float* __restrict__ par,
    bf16* __restrict__ xl2, bf16* __restrict__ xr2) {
  __shared__ float hs[16][F1];
  const int t = threadIdx.x;
  const int node0 = blockIdx.x * 16;
  for (int i = t; i < 16 * F1; i += 128) {
    int n = i >> 8, k = i & 255;
    int node = node0 + n;
    hs[n][k] = (node < N_NODES) ? (float)h[(size_t)node * F1 + k] : 0.f;
  }
  __syncthreads();
  const float* Wl = par + P_WL2;
  const float* Wr = par + P_WR2;
  float accl[16], accr[16];
#pragma unroll
  for (int n = 0; n < 16; n++) { accl[n] = 0.f; accr[n] = 0.f; }
#pragma unroll 4
  for (int k = 0; k < F1; k++) {
    float wl = Wl[k * F2 + t];
    float wr = Wr[k * F2 + t];
#pragma unroll
    for (int n = 0; n < 16; n++) {
      float hv = hs[n][k];
      accl[n] += hv * wl;
      accr[n] += hv * wr;
    }
  }
  float bL = par[P_BL2 + t], bR = par[P_BR2 + t];
  for (int n = 0; n < 16; n++) {
    int node = node0 + n;
    if (node >= N_NODES) break;
    xl2[(size_t)node * F2 + t] = (bf16)(accl[n] + bL);
    xr2[(size_t)node * F2 + t] = (bf16)(accr[n] + bR);
  }
}

// ---------------- CSR build ----------------
__global__ void count_k(const int* __restrict__ ei, int* __restrict__ cnt) {
  int e = blockIdx.x * 256 + threadIdx.x;
  if (e >= TOT_E) return;
  int dst = (e < N_EDGES) ? ei[N_EDGES + e] : (e - N_EDGES);
  atomicAdd(&cnt[dst], 1);
}

__global__ __launch_bounds__(1024) void scan_k(const int* __restrict__ cnt,
                                               int* __restrict__ offs,
                                               int* __restrict__ cursor) {
  __shared__ int wsum[16];
  __shared__ int carry_s;
  const int t = threadIdx.x;
  const int lane = t & 63, w = t >> 6;
  if (t == 0) carry_s = 0;
  __syncthreads();
  for (int base = 0; base < N_NODES; base += 1024) {
    int idx = base + t;
    int v = (idx < N_NODES) ? cnt[idx] : 0;
    int s = v;
#pragma unroll
    for (int off = 1; off < 64; off <<= 1) {
      int u = __shfl_up(s, off, 64);
      if (lane >= off) s += u;
    }
    if (lane == 63) wsum[w] = s;
    __syncthreads();
    int prefix = carry_s;
    for (int i = 0; i < w; i++) prefix += wsum[i];
    int excl = prefix + s - v;
    if (idx < N_NODES) { offs[idx] = excl; cursor[idx] = excl; }
    __syncthreads();
    if (t == 1023) carry_s = prefix + s;
    __syncthreads();
  }
  if (t == 0) offs[N_NODES] = carry_s;
}

__global__ void scatter_k(const int* __restrict__ ei, int* __restrict__ cursor,
                          int* __restrict__ csr) {
  int e = blockIdx.x * 256 + threadIdx.x;
  if (e >= TOT_E) return;
  int src, dst;
  if (e < N_EDGES) { src = ei[e]; dst = ei[N_EDGES + e]; }
  else             { src = dst = e - N_EDGES; }
  int pos = atomicAdd(&cursor[dst], 1);
  csr[pos] = src;
}

// ---------------- layer-1 aggregation ----------------
// Block = 256 = 4 waves, wave w = head w. Within a wave: 8 groups x 8 lanes;
// group g handles edge base+g, lane sl holds channels chbase..chbase+7 (16B load).
__global__ __launch_bounds__(256) void agg1_k(
    const bf16* __restrict__ xl1, const bf16* __restrict__ xr1,
    const float* __restrict__ par,
    const int* __restrict__ offs, const int* __restrict__ csr,
    bf16* __restrict__ hout) {
  const int dst = blockIdx.x;
  const int t = threadIdx.x;
  const int w = t >> 6;
  const int lane = t & 63;
  const int g = lane >> 3;
  const int sl = lane & 7;
  const int chbase = w * HIDC + sl * 8;

  float r[8], a[8];
  load8bf(xr1 + (size_t)dst * F1 + chbase, r);
  float4 a0 = *(const float4*)(par + P_ATT1 + chbase);
  float4 a1 = *(const float4*)(par + P_ATT1 + chbase + 4);
  a[0]=a0.x; a[1]=a0.y; a[2]=a0.z; a[3]=a0.w;
  a[4]=a1.x; a[5]=a1.y; a[6]=a1.z; a[7]=a1.w;

  const int e0 = offs[dst], e1 = offs[dst + 1];
  float acc[8];
#pragma unroll
  for (int j = 0; j < 8; j++) acc[j] = 0.f;
  float denom = 0.f;

  for (int base = e0; base < e1; base += 8) {
    int e = base + g;
    float v[8], lt;
    if (e < e1) {
      int src = csr[e];
      load8bf(xl1 + (size_t)src * F1 + chbase, v);
      lt = 0.f;
#pragma unroll
      for (int j = 0; j < 8; j++)
        lt = __builtin_fmaf(lrelu(v[j] + r[j]), a[j], lt);
    } else {
#pragma unroll
      for (int j = 0; j < 8; j++) v[j] = 0.f;
      lt = -1e30f;
    }
    lt += __shfl_xor(lt, 1, 64);
    lt += __shfl_xor(lt, 2, 64);
    lt += __shfl_xor(lt, 4, 64);
    float p = __expf(fminf(lt, 60.f));   // logits are O(1); invalid groups -> exp(-3e31)=0
    denom += p;
#pragma unroll
    for (int j = 0; j < 8; j++) acc[j] = __builtin_fmaf(p, v[j], acc[j]);
  }

  // combine the 8 edge-groups (once per node)
#pragma unroll
  for (int m = 8; m <= 32; m <<= 1) {
    denom += __shfl_xor(denom, m, 64);
#pragma unroll
    for (int j = 0; j < 8; j++) acc[j] += __shfl_xor(acc[j], m, 64);
  }

  if (g == 0) {
    float inv = 1.f / (denom + EPS_A);
    __align__(16) bf16 ob[8];
#pragma unroll
    for (int j = 0; j < 8; j++) {
      float o = fmaxf(__builtin_fmaf(acc[j], inv, 0.f) + par[P_BIAS1 + chbase + j], 0.f);
      ob[j] = (bf16)o;
    }
    *(uint4*)(hout + (size_t)dst * F1 + chbase) = *(uint4*)ob;
  }
}

// ---------------- layer-2 aggregation: 4 waves/block, wave = one dst ----------------
// Within a wave: 8 groups x 8 lanes; lane sl holds 16 channels (2 x 16B loads).
__global__ __launch_bounds__(256) void agg2_k(
    const bf16* __restrict__ xl2, const bf16* __restrict__ xr2,
    const float* __restrict__ par,
    const int* __restrict__ offs, const int* __restrict__ csr,
    bf16* __restrict__ h2) {
  const int dst = blockIdx.x * 4 + (threadIdx.x >> 6);
  if (dst >= N_NODES) return;
  const int lane = threadIdx.x & 63;
  const int g = lane >> 3;
  const int sl = lane & 7;
  const int chb = sl * 16;

  float r[16], a[16];
  load8bf(xr2 + (size_t)dst * F2 + chb, r);
  load8bf(xr2 + (size_t)dst * F2 + chb + 8, r + 8);
#pragma unroll
  for (int j = 0; j < 16; j += 4) {
    float4 av = *(const float4*)(par + P_ATT2 + chb + j);
    a[j]=av.x; a[j+1]=av.y; a[j+2]=av.z; a[j+3]=av.w;
  }

  const int e0 = offs[dst], e1 = offs[dst + 1];
  float acc[16];
#pragma unroll
  for (int j = 0; j < 16; j++) acc[j] = 0.f;
  float denom = 0.f;

  for (int base = e0; base < e1; base += 8) {
    int e = base + g;
    float v[16], lt;
    if (e < e1) {
      int src = csr[e];
      load8bf(xl2 + (size_t)src * F2 + chb, v);
      load8bf(xl2 + (size_t)src * F2 + chb + 8, v + 8);
      lt = 0.f;
#pragma unroll
      for (int j = 0; j < 16; j++)
        lt = __builtin_fmaf(lrelu(v[j] + r[j]), a[j], lt);
    } else {
#pragma unroll
      for (int j = 0; j < 16; j++) v[j] = 0.f;
      lt = -1e30f;
    }
    lt += __shfl_xor(lt, 1, 64);
    lt += __shfl_xor(lt, 2, 64);
    lt += __shfl_xor(lt, 4, 64);
    float p = __expf(fminf(lt, 60.f));
    denom += p;
#pragma unroll
    for (int j = 0; j < 16; j++) acc[j] = __builtin_fmaf(p, v[j], acc[j]);
  }

#pragma unroll
  for (int m = 8; m <= 32; m <<= 1) {
    denom += __shfl_xor(denom, m, 64);
#pragma unroll
    for (int j = 0; j < 16; j++) acc[j] += __shfl_xor(acc[j], m, 64);
  }

  if (g == 0) {
    float inv = 1.f / (denom + EPS_A);
    __align__(16) bf16 ob[16];
#pragma unroll
    for (int j = 0; j < 16; j++) {
      float o = fmaxf(acc[j] * inv + par[P_BIAS2 + chb + j], 0.f);
      ob[j] = (bf16)o;
    }
    *(uint4*)(h2 + (size_t)dst * F2 + chb)     = *(uint4*)ob;
    *(uint4*)(h2 + (size_t)dst * F2 + chb + 8) = *(uint4*)(ob + 8);
  }
}

// ---------------- pooling (batch is sorted) ----------------
__global__ void binit_k(int* __restrict__ gs, int* __restrict__ ge) {
  int g = threadIdx.x;
  if (g < NGRAPH) { gs[g] = INT_MAX; ge[g] = -1; }
}

__global__ void bounds_k(const int* __restrict__ batch,
                         int* __restrict__ gs, int* __restrict__ ge) {
  int n = blockIdx.x * 256 + threadIdx.x;
  if (n >= N_NODES) return;
  int b = batch[n];
  atomicMin(&gs[b], n);
  atomicMax(&ge[b], n);
}

__global__ __launch_bounds__(256) void pool_k(
    const bf16* __restrict__ h2, const int* __restrict__ gs,
    const int* __restrict__ ge, const int* __restrict__ flag,
    void* __restrict__ out) {
  const int g = blockIdx.x;
  const int t = threadIdx.x;
  const int c = t & 127, half = t >> 7;
  const int s = gs[g], e = ge[g];
  float sum = 0.f;
  for (int n = s + half; n <= e; n += 2)
    sum += (float)h2[(size_t)n * F2 + c];
  __shared__ float red[128];
  if (half == 1) red[c] = sum;
  __syncthreads();
  if (half == 0) {
    float tot = sum + red[c];
    float cnt = (e >= s) ? (float)(e - s + 1) : 1.f;
    float v = tot / cnt;
    if (*flag) ((float*)out)[g * F2 + c] = v;
    else       ((bf16*)out)[g * F2 + c] = (bf16)v;
  }
}

// ---------------- launch ----------------
extern "C" void kernel_launch(void* const* d_in, const int* in_sizes, int n_in,
                              void* d_out, int out_size, void* d_ws, size_t ws_size,
                              hipStream_t stream) {
  (void)in_sizes; (void)n_in; (void)out_size; (void)ws_size;
  const void* x     = d_in[0];
  const int*  ei    = (const int*)d_in[1];
  const int*  batch = (const int*)d_in[2];

  char* ws = (char*)d_ws;
  int*   flag = (int*)(ws + OFF_FLAG);
  float* par  = (float*)(ws + OFF_PAR);
  bf16* xl1 = (bf16*)(ws + OFF_XL1);
  bf16* xr1 = (bf16*)(ws + OFF_XR1);
  bf16* h   = (bf16*)(ws + OFF_H);
  bf16* xl2 = (bf16*)(ws + OFF_XL2);
  bf16* xr2 = (bf16*)(ws + OFF_XR2);
  bf16* h2  = (bf16*)(ws + OFF_H2);    // overlaps xl1 (dead after agg1)
  int* cnt    = (int*)(ws + OFF_CNT);
  int* offs   = (int*)(ws + OFF_OFFS);
  int* cursor = (int*)(ws + OFF_CUR);
  int* csr    = (int*)(ws + OFF_CSR);
  int* gs     = (int*)(ws + OFF_GS);
  int* ge     = (int*)(ws + OFF_GE);

  hipMemsetAsync(cnt, 0, (size_t)N_NODES * 4, stream);

  detect_k<<<1, 64, 0, stream>>>(x, flag);

  CvtArgs ca;
  const int srcidx[12] = {3, 4, 5, 6, 7, 8, 9, 10, 11, 12, 13, 14};
  const int ns[12]     = {IN_F * F1, F1, IN_F * F1, F1, F1, F1,
                          F1 * F2, F2, F1 * F2, F2, F2, F2};
  const int doff[12]   = {P_WL1, P_BL1, P_WR1, P_BR1, P_ATT1, P_BIAS1,
                          P_WL2, P_BL2, P_WR2, P_BR2, P_ATT2, P_BIAS2};
  for (int i = 0; i < 12; i++) { ca.src[i] = d_in[srcidx[i]]; ca.n[i] = ns[i]; ca.dstoff[i] = doff[i]; }
  convert_k<<<dim3((F1 * F2 + 255) / 256, 12), 256, 0, stream>>>(ca, flag, par);

  const int nb16 = (N_NODES + 15) / 16;
  const int ebl  = (TOT_E + 255) / 256;

  gemm1_k<<<nb16, 256, 0, stream>>>(flag, x, par, xl1, xr1);
  count_k<<<ebl, 256, 0, stream>>>(ei, cnt);
  scan_k<<<1, 1024, 0, stream>>>(cnt, offs, cursor);
  scatter_k<<<ebl, 256, 0, stream>>>(ei, cursor, csr);
  binit_k<<<1, 128, 0, stream>>>(gs, ge);
  bounds_k<<<(N_NODES + 255) / 256, 256, 0, stream>>>(batch, gs, ge);
  agg1_k<<<N_NODES, 256, 0, stream>>>(xl1, xr1, par, offs, csr, h);
  gemm2_k<<<nb16, 128, 0, stream>>>(h, par, xl2, xr2);
  agg2_k<<<(N_NODES + 3) / 4, 256, 0, stream>>>(xl2, xr2, par, offs, csr, h2);
  pool_k<<<NGRAPH, 256, 0, stream>>>(h2, gs, ge, flag, d_out);
}

// Round 4
// 742.098 us; speedup vs baseline: 1.2796x; 1.0432x over previous
//
#include <hip/hip_runtime.h>
#include <hip/hip_bf16.h>
#include <limits.h>

// ---------------- problem constants ----------------
#define N_NODES 50000
#define N_EDGES 800000
#define TOT_E   (N_EDGES + N_NODES)   // with self loops
#define IN_F    38
#define HIDC    64
#define NH      4
#define F1      256                    // NH*HIDC
#define F2      128                    // OUT
#define NGRAPH  128
#define NEG_SLOPE 0.2f
#define EPS_A   1e-16f

typedef __hip_bfloat16 bf16;
typedef __attribute__((ext_vector_type(8))) short short8;
typedef __attribute__((ext_vector_type(4))) float f32x4;

// ---------------- ws layout ----------------
constexpr size_t al256(size_t x) { return (x + 255) & ~(size_t)255; }

// converted-params element offsets (f32 elements)
#define P_WL1   0
#define P_BL1   (P_WL1 + IN_F * F1)
#define P_WR1   (P_BL1 + F1)
#define P_BR1   (P_WR1 + IN_F * F1)
#define P_ATT1  (P_BR1 + F1)
#define P_BIAS1 (P_ATT1 + F1)
#define P_WL2   (P_BIAS1 + F1)
#define P_BL2   (P_WL2 + F1 * F2)
#define P_WR2   (P_BL2 + F2)
#define P_BR2   (P_WR2 + F1 * F2)
#define P_ATT2  (P_BR2 + F2)
#define P_BIAS2 (P_ATT2 + F2)
#define P_TOTAL (P_BIAS2 + F2)

constexpr size_t OFF_FLAG = 0;
constexpr size_t OFF_PAR  = 256;
constexpr size_t OFF_XL1  = OFF_PAR + al256((size_t)P_TOTAL * 4);   // reused as h2 later
constexpr size_t OFF_XR1  = OFF_XL1 + al256((size_t)N_NODES * F1 * 2);
constexpr size_t OFF_H    = OFF_XR1 + al256((size_t)N_NODES * F1 * 2);
constexpr size_t OFF_XL2  = OFF_H   + al256((size_t)N_NODES * F1 * 2);
constexpr size_t OFF_XR2  = OFF_XL2 + al256((size_t)N_NODES * F2 * 2);
constexpr size_t OFF_CNT  = OFF_XR2 + al256((size_t)N_NODES * F2 * 2);
constexpr size_t OFF_OFFS = OFF_CNT + al256((size_t)N_NODES * 4);
constexpr size_t OFF_CUR  = OFF_OFFS+ al256((size_t)(N_NODES + 1) * 4);
constexpr size_t OFF_CSR  = OFF_CUR + al256((size_t)(N_NODES + 1) * 4);
constexpr size_t OFF_GS   = OFF_CSR + al256((size_t)TOT_E * 4);
constexpr size_t OFF_GE   = OFF_GS  + al256((size_t)NGRAPH * 4);
constexpr size_t OFF_WT1  = OFF_GE  + al256((size_t)NGRAPH * 4);    // 512x64 bf16
constexpr size_t OFF_WT2  = OFF_WT1 + al256((size_t)512 * 64 * 2);  // 256x256 bf16
constexpr size_t OFF_H2   = OFF_XL1;  // xl1 dead after agg1
constexpr size_t OFF_XB   = OFF_H;    // xb (N x 64 bf16) dead before agg1 writes h

// ---------------- helpers ----------------
__device__ __forceinline__ void load8bf(const bf16* __restrict__ p, float* f) {
  uint4 q = *(const uint4*)p;
  unsigned v[4] = {q.x, q.y, q.z, q.w};
#pragma unroll
  for (int i = 0; i < 4; i++) {
    f[2*i]   = __uint_as_float(v[i] << 16);
    f[2*i+1] = __uint_as_float(v[i] & 0xffff0000u);
  }
}

__device__ __forceinline__ float lrelu(float s) {
  return fmaxf(s, 0.f) + NEG_SLOPE * fminf(s, 0.f);
}

// ---------------- dtype detection (1 = f32 inputs, 0 = bf16) ----------------
__global__ void detect_k(const void* __restrict__ x, int* __restrict__ flag) {
  const int lane = threadIdx.x;
  const unsigned short* u = (const unsigned short*)x;
  unsigned short b = u[lane];
  int e = (b >> 7) & 0xFF;
  int insane = !((e == 0) || (e >= 96 && e <= 158));
#pragma unroll
  for (int off = 32; off > 0; off >>= 1) insane += __shfl_xor(insane, off, 64);
  if (lane == 0) *flag = (insane > 8) ? 1 : 0;
}

// ---------------- param conversion -> f32 scratch ----------------
struct CvtArgs { const void* src[12]; int n[12]; int dstoff[12]; };

__global__ void convert_k(CvtArgs a, const int* __restrict__ flag,
                          float* __restrict__ dst) {
  const int row = blockIdx.y;
  const int i = blockIdx.x * 256 + threadIdx.x;
  if (i >= a.n[row]) return;
  float v = (*flag) ? ((const float*)a.src[row])[i]
                    : (float)((const bf16*)a.src[row])[i];
  dst[a.dstoff[row] + i] = v;
}

// ---------------- MFMA prep: x -> xb (N x 64 bf16, zero-padded K) ----------------
__global__ void xprep_k(const int* __restrict__ flag, const void* __restrict__ x,
                        bf16* __restrict__ xb) {
  int i = blockIdx.x * 256 + threadIdx.x;       // i = n*64 + k
  if (i >= N_NODES * 64) return;
  int n = i >> 6, k = i & 63;
  float v = 0.f;
  if (k < IN_F) {
    int idx = n * IN_F + k;
    v = (*flag) ? ((const float*)x)[idx] : (float)((const bf16*)x)[idx];
  }
  xb[i] = (bf16)v;
}

// Wt1[n][k]: n in [0,512) (n<256 -> Wl1 col n, else Wr1 col n-256), k in [0,64) zero-padded
__global__ void wprep1_k(const int* __restrict__ flag,
                         const void* __restrict__ Wl, const void* __restrict__ Wr,
                         bf16* __restrict__ wt1) {
  int i = blockIdx.x * 256 + threadIdx.x;       // i = n*64 + k
  if (i >= 512 * 64) return;
  int n = i >> 6, k = i & 63;
  float v = 0.f;
  if (k < IN_F) {
    const void* W = (n < F1) ? Wl : Wr;
    int col = (n < F1) ? n : n - F1;
    int idx = k * F1 + col;
    v = (*flag) ? ((const float*)W)[idx] : (float)((const bf16*)W)[idx];
  }
  wt1[i] = (bf16)v;
}

// Wt2[n][k]: n in [0,256) (n<128 -> Wl2 col n, else Wr2 col n-128), k in [0,256)
__global__ void wprep2_k(const int* __restrict__ flag,
                         const void* __restrict__ Wl, const void* __restrict__ Wr,
                         bf16* __restrict__ wt2) {
  int i = blockIdx.x * 256 + threadIdx.x;       // i = n*256 + k
  if (i >= 256 * 256) return;
  int n = i >> 8, k = i & 255;
  const void* W = (n < F2) ? Wl : Wr;
  int col = (n < F2) ? n : n - F2;
  int idx = k * F2 + col;
  float v = (*flag) ? ((const float*)W)[idx] : (float)((const bf16*)W)[idx];
  wt2[i] = (bf16)v;
}

// ---------------- GEMM 1 (MFMA): xb(N,64) @ Wt1^T -> xl1|xr1 (N,256 each) ----------------
// Block = 4 waves. Wave w: rows blk*32 + (w&1)*16, cols (w>>1)*256 .. +255 (16 N-tiles).
__global__ __launch_bounds__(256) void gemm1_mfma_k(
    const bf16* __restrict__ xb, const bf16* __restrict__ wt1,
    const float* __restrict__ par,
    bf16* __restrict__ xl1, bf16* __restrict__ xr1) {
  const int w = threadIdx.x >> 6, lane = threadIdx.x & 63;
  const int m0 = blockIdx.x * 32 + (w & 1) * 16;
  const int colbase = (w >> 1) * 256;
  const int lm = lane & 15, lk = lane >> 4;

  int arow = m0 + lm; if (arow >= N_NODES) arow = N_NODES - 1;
  const short8 a0 = *(const short8*)(xb + (size_t)arow * 64 + lk * 8);
  const short8 a1 = *(const short8*)(xb + (size_t)arow * 64 + 32 + lk * 8);

  f32x4 acc[16];
  const f32x4 z = {0.f, 0.f, 0.f, 0.f};
#pragma unroll
  for (int nt = 0; nt < 16; nt++) acc[nt] = z;

#pragma unroll
  for (int nt = 0; nt < 16; nt++) {
    int n = colbase + nt * 16 + lm;
    short8 b0 = *(const short8*)(wt1 + (size_t)n * 64 + lk * 8);
    short8 b1 = *(const short8*)(wt1 + (size_t)n * 64 + 32 + lk * 8);
    acc[nt] = __builtin_amdgcn_mfma_f32_16x16x32_bf16(a0, b0, acc[nt], 0, 0, 0);
    acc[nt] = __builtin_amdgcn_mfma_f32_16x16x32_bf16(a1, b1, acc[nt], 0, 0, 0);
  }

  const int r0 = m0 + (lane >> 4) * 4;
#pragma unroll
  for (int nt = 0; nt < 16; nt++) {
    int col = colbase + nt * 16 + lm;
    bf16* dst = (col < F1) ? xl1 : xr1;
    int c = (col < F1) ? col : col - F1;
    float bv = (col < F1) ? par[P_BL1 + c] : par[P_BR1 + c];
#pragma unroll
    for (int reg = 0; reg < 4; reg++) {
      int row = r0 + reg;
      if (row < N_NODES)
        dst[(size_t)row * F1 + c] = (bf16)(acc[nt][reg] + bv);
    }
  }
}

// ---------------- GEMM 2 (MFMA): h(N,256) @ Wt2^T -> xl2|xr2 (N,128 each) ----------------
// Block = 4 waves. Wave w: rows blk*32 + (w&1)*16, cols (w>>1)*128 .. +127 (8 N-tiles).
__global__ __launch_bounds__(256) void gemm2_mfma_k(
    const bf16* __restrict__ h, const bf16* __restrict__ wt2,
    const float* __restrict__ par,
    bf16* __restrict__ xl2, bf16* __restrict__ xr2) {
  const int w = threadIdx.x >> 6, lane = threadIdx.x & 63;
  const int m0 = blockIdx.x * 32 + (w & 1) * 16;
  const int colbase = (w >> 1) * 128;
  const int lm = lane & 15, lk = lane >> 4;

  int arow = m0 + lm; if (arow >= N_NODES) arow = N_NODES - 1;
  const bf16* hrow = h + (size_t)arow * F1 + lk * 8;

  f32x4 acc[8];
  const f32x4 z = {0.f, 0.f, 0.f, 0.f};
#pragma unroll
  for (int nt = 0; nt < 8; nt++) acc[nt] = z;

#pragma unroll
  for (int kk = 0; kk < 256; kk += 32) {
    short8 a = *(const short8*)(hrow + kk);
#pragma unroll
    for (int nt = 0; nt < 8; nt++) {
      int n = colbase + nt * 16 + lm;
      short8 b = *(const short8*)(wt2 + (size_t)n * 256 + kk + lk * 8);
      acc[nt] = __builtin_amdgcn_mfma_f32_16x16x32_bf16(a, b, acc[nt], 0, 0, 0);
    }
  }

  const int r0 = m0 + (lane >> 4) * 4;
#pragma unroll
  for (int nt = 0; nt < 8; nt++) {
    int col = colbase + nt * 16 + lm;
    bf16* dst = (col < F2) ? xl2 : xr2;
    int c = (col < F2) ? col : col - F2;
    float bv = (col < F2) ? par[P_BL2 + c] : par[P_BR2 + c];
#pragma unroll
    for (int reg = 0; reg < 4; reg++) {
      int row = r0 + reg;
      if (row < N_NODES)
        dst[(size_t)row * F2 + c] = (bf16)(acc[nt][reg] + bv);
    }
  }
}

// ---------------- CSR build ----------------
__global__ void count_k(const int* __restrict__ ei, int* __restrict__ cnt) {
  int e = blockIdx.x * 256 + threadIdx.x;
  if (e >= TOT_E) return;
  int dst = (e < N_EDGES) ? ei[N_EDGES + e] : (e - N_EDGES);
  atomicAdd(&cnt[dst], 1);
}

__global__ __launch_bounds__(1024) void scan_k(const int* __restrict__ cnt,
                                               int* __restrict__ offs,
                                               int* __restrict__ cursor) {
  __shared__ int wsum[16];
  __shared__ int carry_s;
  const int t = threadIdx.x;
  const int lane = t & 63, w = t >> 6;
  if (t == 0) carry_s = 0;
  __syncthreads();
  for (int base = 0; base < N_NODES; base += 1024) {
    int idx = base + t;
    int v = (idx < N_NODES) ? cnt[idx] : 0;
    int s = v;
#pragma unroll
    for (int off = 1; off < 64; off <<= 1) {
      int u = __shfl_up(s, off, 64);
      if (lane >= off) s += u;
    }
    if (lane == 63) wsum[w] = s;
    __syncthreads();
    int prefix = carry_s;
    for (int i = 0; i < w; i++) prefix += wsum[i];
    int excl = prefix + s - v;
    if (idx < N_NODES) { offs[idx] = excl; cursor[idx] = excl; }
    __syncthreads();
    if (t == 1023) carry_s = prefix + s;
    __syncthreads();
  }
  if (t == 0) offs[N_NODES] = carry_s;
}

__global__ void scatter_k(const int* __restrict__ ei, int* __restrict__ cursor,
                          int* __restrict__ csr) {
  int e = blockIdx.x * 256 + threadIdx.x;
  if (e >= TOT_E) return;
  int src, dst;
  if (e < N_EDGES) { src = ei[e]; dst = ei[N_EDGES + e]; }
  else             { src = dst = e - N_EDGES; }
  int pos = atomicAdd(&cursor[dst], 1);
  csr[pos] = src;
}

// ---------------- layer-1 aggregation ----------------
__global__ __launch_bounds__(256) void agg1_k(
    const bf16* __restrict__ xl1, const bf16* __restrict__ xr1,
    const float* __restrict__ par,
    const int* __restrict__ offs, const int* __restrict__ csr,
    bf16* __restrict__ hout) {
  const int dst = blockIdx.x;
  const int t = threadIdx.x;
  const int w = t >> 6;
  const int lane = t & 63;
  const int g = lane >> 3;
  const int sl = lane & 7;
  const int chbase = w * HIDC + sl * 8;

  float r[8], a[8];
  load8bf(xr1 + (size_t)dst * F1 + chbase, r);
  float4 a0 = *(const float4*)(par + P_ATT1 + chbase);
  float4 a1 = *(const float4*)(par + P_ATT1 + chbase + 4);
  a[0]=a0.x; a[1]=a0.y; a[2]=a0.z; a[3]=a0.w;
  a[4]=a1.x; a[5]=a1.y; a[6]=a1.z; a[7]=a1.w;

  const int e0 = offs[dst], e1 = offs[dst + 1];
  float acc[8];
#pragma unroll
  for (int j = 0; j < 8; j++) acc[j] = 0.f;
  float denom = 0.f;

  for (int base = e0; base < e1; base += 8) {
    int e = base + g;
    float v[8], lt;
    if (e < e1) {
      int src = csr[e];
      load8bf(xl1 + (size_t)src * F1 + chbase, v);
      lt = 0.f;
#pragma unroll
      for (int j = 0; j < 8; j++)
        lt = __builtin_fmaf(lrelu(v[j] + r[j]), a[j], lt);
    } else {
#pragma unroll
      for (int j = 0; j < 8; j++) v[j] = 0.f;
      lt = -1e30f;
    }
    lt += __shfl_xor(lt, 1, 64);
    lt += __shfl_xor(lt, 2, 64);
    lt += __shfl_xor(lt, 4, 64);
    float p = __expf(fminf(lt, 60.f));
    denom += p;
#pragma unroll
    for (int j = 0; j < 8; j++) acc[j] = __builtin_fmaf(p, v[j], acc[j]);
  }

#pragma unroll
  for (int m = 8; m <= 32; m <<= 1) {
    denom += __shfl_xor(denom, m, 64);
#pragma unroll
    for (int j = 0; j < 8; j++) acc[j] += __shfl_xor(acc[j], m, 64);
  }

  if (g == 0) {
    float inv = 1.f / (denom + EPS_A);
    __align__(16) bf16 ob[8];
#pragma unroll
    for (int j = 0; j < 8; j++) {
      float o = fmaxf(__builtin_fmaf(acc[j], inv, 0.f) + par[P_BIAS1 + chbase + j], 0.f);
      ob[j] = (bf16)o;
    }
    *(uint4*)(hout + (size_t)dst * F1 + chbase) = *(uint4*)ob;
  }
}

// ---------------- layer-2 aggregation ----------------
__global__ __launch_bounds__(256) void agg2_k(
    const bf16* __restrict__ xl2, const bf16* __restrict__ xr2,
    const float* __restrict__ par,
    const int* __restrict__ offs, const int* __restrict__ csr,
    bf16* __restrict__ h2) {
  const int dst = blockIdx.x * 4 + (threadIdx.x >> 6);
  if (dst >= N_NODES) return;
  const int lane = threadIdx.x & 63;
  const int g = lane >> 3;
  const int sl = lane & 7;
  const int chb = sl * 16;

  float r[16], a[16];
  load8bf(xr2 + (size_t)dst * F2 + chb, r);
  load8bf(xr2 + (size_t)dst * F2 + chb + 8, r + 8);
#pragma unroll
  for (int j = 0; j < 16; j += 4) {
    float4 av = *(const float4*)(par + P_ATT2 + chb + j);
    a[j]=av.x; a[j+1]=av.y; a[j+2]=av.z; a[j+3]=av.w;
  }

  const int e0 = offs[dst], e1 = offs[dst + 1];
  float acc[16];
#pragma unroll
  for (int j = 0; j < 16; j++) acc[j] = 0.f;
  float denom = 0.f;

  for (int base = e0; base < e1; base += 8) {
    int e = base + g;
    float v[16], lt;
    if (e < e1) {
      int src = csr[e];
      load8bf(xl2 + (size_t)src * F2 + chb, v);
      load8bf(xl2 + (size_t)src * F2 + chb + 8, v + 8);
      lt = 0.f;
#pragma unroll
      for (int j = 0; j < 16; j++)
        lt = __builtin_fmaf(lrelu(v[j] + r[j]), a[j], lt);
    } else {
#pragma unroll
      for (int j = 0; j < 16; j++) v[j] = 0.f;
      lt = -1e30f;
    }
    lt += __shfl_xor(lt, 1, 64);
    lt += __shfl_xor(lt, 2, 64);
    lt += __shfl_xor(lt, 4, 64);
    float p = __expf(fminf(lt, 60.f));
    denom += p;
#pragma unroll
    for (int j = 0; j < 16; j++) acc[j] = __builtin_fmaf(p, v[j], acc[j]);
  }

#pragma unroll
  for (int m = 8; m <= 32; m <<= 1) {
    denom += __shfl_xor(denom, m, 64);
#pragma unroll
    for (int j = 0; j < 16; j++) acc[j] += __shfl_xor(acc[j], m, 64);
  }

  if (g == 0) {
    float inv = 1.f / (denom + EPS_A);
    __align__(16) bf16 ob[16];
#pragma unroll
    for (int j = 0; j < 16; j++) {
      float o = fmaxf(acc[j] * inv + par[P_BIAS2 + chb + j], 0.f);
      ob[j] = (bf16)o;
    }
    *(uint4*)(h2 + (size_t)dst * F2 + chb)     = *(uint4*)ob;
    *(uint4*)(h2 + (size_t)dst * F2 + chb + 8) = *(uint4*)(ob + 8);
  }
}

// ---------------- pooling (batch is sorted) ----------------
__global__ void binit_k(int* __restrict__ gs, int* __restrict__ ge) {
  int g = threadIdx.x;
  if (g < NGRAPH) { gs[g] = INT_MAX; ge[g] = -1; }
}

__global__ void bounds_k(const int* __restrict__ batch,
                         int* __restrict__ gs, int* __restrict__ ge) {
  int n = blockIdx.x * 256 + threadIdx.x;
  if (n >= N_NODES) return;
  int b = batch[n];
  atomicMin(&gs[b], n);
  atomicMax(&ge[b], n);
}

__global__ __launch_bounds__(256) void pool_k(
    const bf16* __restrict__ h2, const int* __restrict__ gs,
    const int* __restrict__ ge, const int* __restrict__ flag,
    void* __restrict__ out) {
  const int g = blockIdx.x;
  const int t = threadIdx.x;
  const int c = t & 127, half = t >> 7;
  const int s = gs[g], e = ge[g];
  float sum = 0.f;
  for (int n = s + half; n <= e; n += 2)
    sum += (float)h2[(size_t)n * F2 + c];
  __shared__ float red[128];
  if (half == 1) red[c] = sum;
  __syncthreads();
  if (half == 0) {
    float tot = sum + red[c];
    float cnt = (e >= s) ? (float)(e - s + 1) : 1.f;
    float v = tot / cnt;
    if (*flag) ((float*)out)[g * F2 + c] = v;
    else       ((bf16*)out)[g * F2 + c] = (bf16)v;
  }
}

// ---------------- launch ----------------
extern "C" void kernel_launch(void* const* d_in, const int* in_sizes, int n_in,
                              void* d_out, int out_size, void* d_ws, size_t ws_size,
                              hipStream_t stream) {
  (void)in_sizes; (void)n_in; (void)out_size; (void)ws_size;
  const void* x     = d_in[0];
  const int*  ei    = (const int*)d_in[1];
  const int*  batch = (const int*)d_in[2];

  char* ws = (char*)d_ws;
  int*   flag = (int*)(ws + OFF_FLAG);
  float* par  = (float*)(ws + OFF_PAR);
  bf16* xl1 = (bf16*)(ws + OFF_XL1);
  bf16* xr1 = (bf16*)(ws + OFF_XR1);
  bf16* h   = (bf16*)(ws + OFF_H);
  bf16* xl2 = (bf16*)(ws + OFF_XL2);
  bf16* xr2 = (bf16*)(ws + OFF_XR2);
  bf16* h2  = (bf16*)(ws + OFF_H2);
  bf16* xb  = (bf16*)(ws + OFF_XB);
  bf16* wt1 = (bf16*)(ws + OFF_WT1);
  bf16* wt2 = (bf16*)(ws + OFF_WT2);
  int* cnt    = (int*)(ws + OFF_CNT);
  int* offs   = (int*)(ws + OFF_OFFS);
  int* cursor = (int*)(ws + OFF_CUR);
  int* csr    = (int*)(ws + OFF_CSR);
  int* gs     = (int*)(ws + OFF_GS);
  int* ge     = (int*)(ws + OFF_GE);

  hipMemsetAsync(cnt, 0, (size_t)N_NODES * 4, stream);

  detect_k<<<1, 64, 0, stream>>>(x, flag);

  CvtArgs ca;
  const int srcidx[12] = {3, 4, 5, 6, 7, 8, 9, 10, 11, 12, 13, 14};
  const int ns[12]     = {IN_F * F1, F1, IN_F * F1, F1, F1, F1,
                          F1 * F2, F2, F1 * F2, F2, F2, F2};
  const int doff[12]   = {P_WL1, P_BL1, P_WR1, P_BR1, P_ATT1, P_BIAS1,
                          P_WL2, P_BL2, P_WR2, P_BR2, P_ATT2, P_BIAS2};
  for (int i = 0; i < 12; i++) { ca.src[i] = d_in[srcidx[i]]; ca.n[i] = ns[i]; ca.dstoff[i] = doff[i]; }
  convert_k<<<dim3((F1 * F2 + 255) / 256, 12), 256, 0, stream>>>(ca, flag, par);

  xprep_k<<<(N_NODES * 64 + 255) / 256, 256, 0, stream>>>(flag, x, xb);
  wprep1_k<<<(512 * 64 + 255) / 256, 256, 0, stream>>>(flag, d_in[3], d_in[5], wt1);
  wprep2_k<<<(256 * 256 + 255) / 256, 256, 0, stream>>>(flag, d_in[9], d_in[11], wt2);

  const int ebl = (TOT_E + 255) / 256;
  const int gblk = (N_NODES + 31) / 32;   // 1563

  gemm1_mfma_k<<<gblk, 256, 0, stream>>>(xb, wt1, par, xl1, xr1);
  count_k<<<ebl, 256, 0, stream>>>(ei, cnt);
  scan_k<<<1, 1024, 0, stream>>>(cnt, offs, cursor);
  scatter_k<<<ebl, 256, 0, stream>>>(ei, cursor, csr);
  binit_k<<<1, 128, 0, stream>>>(gs, ge);
  bounds_k<<<(N_NODES + 255) / 256, 256, 0, stream>>>(batch, gs, ge);
  agg1_k<<<N_NODES, 256, 0, stream>>>(xl1, xr1, par, offs, csr, h);
  gemm2_mfma_k<<<gblk, 256, 0, stream>>>(h, wt2, par, xl2, xr2);
  agg2_k<<<(N_NODES + 3) / 4, 256, 0, stream>>>(xl2, xr2, par, offs, csr, h2);
  pool_k<<<NGRAPH, 256, 0, stream>>>(h2, gs, ge, flag, d_out);
}

// Round 5
// 593.014 us; speedup vs baseline: 1.6012x; 1.2514x over previous
//
#include <hip/hip_runtime.h>
#include <hip/hip_bf16.h>
#include <limits.h>

// ---------------- problem constants ----------------
#define N_NODES 50000
#define N_EDGES 800000
#define TOT_E   (N_EDGES + N_NODES)   // with self loops
#define IN_F    38
#define HIDC    64
#define NH      4
#define F1      256                    // NH*HIDC
#define F2      128                    // OUT
#define NGRAPH  128
#define NEG_SLOPE 0.2f
#define EPS_A   1e-16f

typedef __hip_bfloat16 bf16;
typedef __attribute__((ext_vector_type(8))) short short8;
typedef __attribute__((ext_vector_type(4))) float f32x4;

// ---------------- ws layout ----------------
constexpr size_t al256(size_t x) { return (x + 255) & ~(size_t)255; }

// converted-params element offsets (f32 elements)
#define P_WL1   0
#define P_BL1   (P_WL1 + IN_F * F1)
#define P_WR1   (P_BL1 + F1)
#define P_BR1   (P_WR1 + IN_F * F1)
#define P_ATT1  (P_BR1 + F1)
#define P_BIAS1 (P_ATT1 + F1)
#define P_WL2   (P_BIAS1 + F1)
#define P_BL2   (P_WL2 + F1 * F2)
#define P_WR2   (P_BL2 + F2)
#define P_BR2   (P_WR2 + F1 * F2)
#define P_ATT2  (P_BR2 + F2)
#define P_BIAS2 (P_ATT2 + F2)
#define P_TOTAL (P_BIAS2 + F2)

constexpr size_t OFF_FLAG = 0;
constexpr size_t OFF_PAR  = 256;
constexpr size_t OFF_XL1  = OFF_PAR + al256((size_t)P_TOTAL * 4);   // reused as h2 later
constexpr size_t OFF_XR1  = OFF_XL1 + al256((size_t)N_NODES * F1 * 2);
constexpr size_t OFF_H    = OFF_XR1 + al256((size_t)N_NODES * F1 * 2);
constexpr size_t OFF_XL2  = OFF_H   + al256((size_t)N_NODES * F1 * 2);
constexpr size_t OFF_XR2  = OFF_XL2 + al256((size_t)N_NODES * F2 * 2);
constexpr size_t OFF_CNT  = OFF_XR2 + al256((size_t)N_NODES * F2 * 2);
constexpr size_t OFF_OFFS = OFF_CNT + al256((size_t)N_NODES * 4);
constexpr size_t OFF_CUR  = OFF_OFFS+ al256((size_t)(N_NODES + 1) * 4);
constexpr size_t OFF_CSR  = OFF_CUR + al256((size_t)(N_NODES + 1) * 4);
constexpr size_t OFF_GS   = OFF_CSR + al256((size_t)TOT_E * 4);
constexpr size_t OFF_GE   = OFF_GS  + al256((size_t)NGRAPH * 4);
constexpr size_t OFF_WT1  = OFF_GE  + al256((size_t)NGRAPH * 4);    // 512x64 bf16
constexpr size_t OFF_WT2  = OFF_WT1 + al256((size_t)512 * 64 * 2);  // 256x256 bf16
constexpr size_t OFF_H2   = OFF_XL1;  // xl1 dead after agg1
constexpr size_t OFF_XB   = OFF_H;    // xb (N x 64 bf16) dead before agg1 writes h

// ---------------- helpers ----------------
__device__ __forceinline__ void load8bf(const bf16* __restrict__ p, float* f) {
  uint4 q = *(const uint4*)p;
  unsigned v[4] = {q.x, q.y, q.z, q.w};
#pragma unroll
  for (int i = 0; i < 4; i++) {
    f[2*i]   = __uint_as_float(v[i] << 16);
    f[2*i+1] = __uint_as_float(v[i] & 0xffff0000u);
  }
}

__device__ __forceinline__ float lrelu(float s) {
  return fmaxf(s, 0.f) + NEG_SLOPE * fminf(s, 0.f);
}

// ---------------- dtype detection (1 = f32 inputs, 0 = bf16) ----------------
__global__ void detect_k(const void* __restrict__ x, int* __restrict__ flag) {
  const int lane = threadIdx.x;
  const unsigned short* u = (const unsigned short*)x;
  unsigned short b = u[lane];
  int e = (b >> 7) & 0xFF;
  int insane = !((e == 0) || (e >= 96 && e <= 158));
#pragma unroll
  for (int off = 32; off > 0; off >>= 1) insane += __shfl_xor(insane, off, 64);
  if (lane == 0) *flag = (insane > 8) ? 1 : 0;
}

// ---------------- param conversion -> f32 scratch ----------------
struct CvtArgs { const void* src[12]; int n[12]; int dstoff[12]; };

__global__ void convert_k(CvtArgs a, const int* __restrict__ flag,
                          float* __restrict__ dst) {
  const int row = blockIdx.y;
  const int i = blockIdx.x * 256 + threadIdx.x;
  if (i >= a.n[row]) return;
  float v = (*flag) ? ((const float*)a.src[row])[i]
                    : (float)((const bf16*)a.src[row])[i];
  dst[a.dstoff[row] + i] = v;
}

// ---------------- MFMA prep: x -> xb (N x 64 bf16, zero-padded K) ----------------
__global__ void xprep_k(const int* __restrict__ flag, const void* __restrict__ x,
                        bf16* __restrict__ xb) {
  int i = blockIdx.x * 256 + threadIdx.x;       // i = n*64 + k
  if (i >= N_NODES * 64) return;
  int n = i >> 6, k = i & 63;
  float v = 0.f;
  if (k < IN_F) {
    int idx = n * IN_F + k;
    v = (*flag) ? ((const float*)x)[idx] : (float)((const bf16*)x)[idx];
  }
  xb[i] = (bf16)v;
}

// Wt1[n][k]: n in [0,512) (n<256 -> Wl1 col n, else Wr1 col n-256), k in [0,64) zero-padded
__global__ void wprep1_k(const int* __restrict__ flag,
                         const void* __restrict__ Wl, const void* __restrict__ Wr,
                         bf16* __restrict__ wt1) {
  int i = blockIdx.x * 256 + threadIdx.x;       // i = n*64 + k
  if (i >= 512 * 64) return;
  int n = i >> 6, k = i & 63;
  float v = 0.f;
  if (k < IN_F) {
    const void* W = (n < F1) ? Wl : Wr;
    int col = (n < F1) ? n : n - F1;
    int idx = k * F1 + col;
    v = (*flag) ? ((const float*)W)[idx] : (float)((const bf16*)W)[idx];
  }
  wt1[i] = (bf16)v;
}

// Wt2[n][k]: n in [0,256) (n<128 -> Wl2 col n, else Wr2 col n-128), k in [0,256)
__global__ void wprep2_k(const int* __restrict__ flag,
                         const void* __restrict__ Wl, const void* __restrict__ Wr,
                         bf16* __restrict__ wt2) {
  int i = blockIdx.x * 256 + threadIdx.x;       // i = n*256 + k
  if (i >= 256 * 256) return;
  int n = i >> 8, k = i & 255;
  const void* W = (n < F2) ? Wl : Wr;
  int col = (n < F2) ? n : n - F2;
  int idx = k * F2 + col;
  float v = (*flag) ? ((const float*)W)[idx] : (float)((const bf16*)W)[idx];
  wt2[i] = (bf16)v;
}

// ---------------- GEMM 1 (MFMA): xb(N,64) @ Wt1^T -> xl1|xr1 (N,256 each) ----------------
__global__ __launch_bounds__(256) void gemm1_mfma_k(
    const bf16* __restrict__ xb, const bf16* __restrict__ wt1,
    const float* __restrict__ par,
    bf16* __restrict__ xl1, bf16* __restrict__ xr1) {
  const int w = threadIdx.x >> 6, lane = threadIdx.x & 63;
  const int m0 = blockIdx.x * 32 + (w & 1) * 16;
  const int colbase = (w >> 1) * 256;
  const int lm = lane & 15, lk = lane >> 4;

  int arow = m0 + lm; if (arow >= N_NODES) arow = N_NODES - 1;
  const short8 a0 = *(const short8*)(xb + (size_t)arow * 64 + lk * 8);
  const short8 a1 = *(const short8*)(xb + (size_t)arow * 64 + 32 + lk * 8);

  f32x4 acc[16];
  const f32x4 z = {0.f, 0.f, 0.f, 0.f};
#pragma unroll
  for (int nt = 0; nt < 16; nt++) acc[nt] = z;

#pragma unroll
  for (int nt = 0; nt < 16; nt++) {
    int n = colbase + nt * 16 + lm;
    short8 b0 = *(const short8*)(wt1 + (size_t)n * 64 + lk * 8);
    short8 b1 = *(const short8*)(wt1 + (size_t)n * 64 + 32 + lk * 8);
    acc[nt] = __builtin_amdgcn_mfma_f32_16x16x32_bf16(a0, b0, acc[nt], 0, 0, 0);
    acc[nt] = __builtin_amdgcn_mfma_f32_16x16x32_bf16(a1, b1, acc[nt], 0, 0, 0);
  }

  const int r0 = m0 + (lane >> 4) * 4;
#pragma unroll
  for (int nt = 0; nt < 16; nt++) {
    int col = colbase + nt * 16 + lm;
    bf16* dst = (col < F1) ? xl1 : xr1;
    int c = (col < F1) ? col : col - F1;
    float bv = (col < F1) ? par[P_BL1 + c] : par[P_BR1 + c];
#pragma unroll
    for (int reg = 0; reg < 4; reg++) {
      int row = r0 + reg;
      if (row < N_NODES)
        dst[(size_t)row * F1 + c] = (bf16)(acc[nt][reg] + bv);
    }
  }
}

// ---------------- GEMM 2 (MFMA): h(N,256) @ Wt2^T -> xl2|xr2 (N,128 each) ----------------
__global__ __launch_bounds__(256) void gemm2_mfma_k(
    const bf16* __restrict__ h, const bf16* __restrict__ wt2,
    const float* __restrict__ par,
    bf16* __restrict__ xl2, bf16* __restrict__ xr2) {
  const int w = threadIdx.x >> 6, lane = threadIdx.x & 63;
  const int m0 = blockIdx.x * 32 + (w & 1) * 16;
  const int colbase = (w >> 1) * 128;
  const int lm = lane & 15, lk = lane >> 4;

  int arow = m0 + lm; if (arow >= N_NODES) arow = N_NODES - 1;
  const bf16* hrow = h + (size_t)arow * F1 + lk * 8;

  f32x4 acc[8];
  const f32x4 z = {0.f, 0.f, 0.f, 0.f};
#pragma unroll
  for (int nt = 0; nt < 8; nt++) acc[nt] = z;

#pragma unroll
  for (int kk = 0; kk < 256; kk += 32) {
    short8 a = *(const short8*)(hrow + kk);
#pragma unroll
    for (int nt = 0; nt < 8; nt++) {
      int n = colbase + nt * 16 + lm;
      short8 b = *(const short8*)(wt2 + (size_t)n * 256 + kk + lk * 8);
      acc[nt] = __builtin_amdgcn_mfma_f32_16x16x32_bf16(a, b, acc[nt], 0, 0, 0);
    }
  }

  const int r0 = m0 + (lane >> 4) * 4;
#pragma unroll
  for (int nt = 0; nt < 8; nt++) {
    int col = colbase + nt * 16 + lm;
    bf16* dst = (col < F2) ? xl2 : xr2;
    int c = (col < F2) ? col : col - F2;
    float bv = (col < F2) ? par[P_BL2 + c] : par[P_BR2 + c];
#pragma unroll
    for (int reg = 0; reg < 4; reg++) {
      int row = r0 + reg;
      if (row < N_NODES)
        dst[(size_t)row * F2 + c] = (bf16)(acc[nt][reg] + bv);
    }
  }
}

// ---------------- CSR build ----------------
__global__ void count_k(const int* __restrict__ ei, int* __restrict__ cnt) {
  int e = blockIdx.x * 256 + threadIdx.x;
  if (e >= TOT_E) return;
  int dst = (e < N_EDGES) ? ei[N_EDGES + e] : (e - N_EDGES);
  atomicAdd(&cnt[dst], 1);
}

__global__ __launch_bounds__(1024) void scan_k(const int* __restrict__ cnt,
                                               int* __restrict__ offs,
                                               int* __restrict__ cursor) {
  __shared__ int wsum[16];
  __shared__ int carry_s;
  const int t = threadIdx.x;
  const int lane = t & 63, w = t >> 6;
  if (t == 0) carry_s = 0;
  __syncthreads();
  for (int base = 0; base < N_NODES; base += 1024) {
    int idx = base + t;
    int v = (idx < N_NODES) ? cnt[idx] : 0;
    int s = v;
#pragma unroll
    for (int off = 1; off < 64; off <<= 1) {
      int u = __shfl_up(s, off, 64);
      if (lane >= off) s += u;
    }
    if (lane == 63) wsum[w] = s;
    __syncthreads();
    int prefix = carry_s;
    for (int i = 0; i < w; i++) prefix += wsum[i];
    int excl = prefix + s - v;
    if (idx < N_NODES) { offs[idx] = excl; cursor[idx] = excl; }
    __syncthreads();
    if (t == 1023) carry_s = prefix + s;
    __syncthreads();
  }
  if (t == 0) offs[N_NODES] = carry_s;
}

__global__ void scatter_k(const int* __restrict__ ei, int* __restrict__ cursor,
                          int* __restrict__ csr) {
  int e = blockIdx.x * 256 + threadIdx.x;
  if (e >= TOT_E) return;
  int src, dst;
  if (e < N_EDGES) { src = ei[e]; dst = ei[N_EDGES + e]; }
  else             { src = dst = e - N_EDGES; }
  int pos = atomicAdd(&cursor[dst], 1);
  csr[pos] = src;
}

// ---------------- layer-1 aggregation ----------------
__global__ __launch_bounds__(256) void agg1_k(
    const bf16* __restrict__ xl1, const bf16* __restrict__ xr1,
    const float* __restrict__ par,
    const int* __restrict__ offs, const int* __restrict__ csr,
    bf16* __restrict__ hout) {
  const int dst = blockIdx.x;
  const int t = threadIdx.x;
  const int w = t >> 6;
  const int lane = t & 63;
  const int g = lane >> 3;
  const int sl = lane & 7;
  const int chbase = w * HIDC + sl * 8;

  float r[8], a[8];
  load8bf(xr1 + (size_t)dst * F1 + chbase, r);
  float4 a0 = *(const float4*)(par + P_ATT1 + chbase);
  float4 a1 = *(const float4*)(par + P_ATT1 + chbase + 4);
  a[0]=a0.x; a[1]=a0.y; a[2]=a0.z; a[3]=a0.w;
  a[4]=a1.x; a[5]=a1.y; a[6]=a1.z; a[7]=a1.w;

  const int e0 = offs[dst], e1 = offs[dst + 1];
  float acc[8];
#pragma unroll
  for (int j = 0; j < 8; j++) acc[j] = 0.f;
  float denom = 0.f;

  for (int base = e0; base < e1; base += 8) {
    int e = base + g;
    float v[8], lt;
    if (e < e1) {
      int src = csr[e];
      load8bf(xl1 + (size_t)src * F1 + chbase, v);
      lt = 0.f;
#pragma unroll
      for (int j = 0; j < 8; j++)
        lt = __builtin_fmaf(lrelu(v[j] + r[j]), a[j], lt);
    } else {
#pragma unroll
      for (int j = 0; j < 8; j++) v[j] = 0.f;
      lt = -1e30f;
    }
    lt += __shfl_xor(lt, 1, 64);
    lt += __shfl_xor(lt, 2, 64);
    lt += __shfl_xor(lt, 4, 64);
    float p = __expf(fminf(lt, 60.f));
    denom += p;
#pragma unroll
    for (int j = 0; j < 8; j++) acc[j] = __builtin_fmaf(p, v[j], acc[j]);
  }

#pragma unroll
  for (int m = 8; m <= 32; m <<= 1) {
    denom += __shfl_xor(denom, m, 64);
#pragma unroll
    for (int j = 0; j < 8; j++) acc[j] += __shfl_xor(acc[j], m, 64);
  }

  if (g == 0) {
    float inv = 1.f / (denom + EPS_A);
    __align__(16) bf16 ob[8];
#pragma unroll
    for (int j = 0; j < 8; j++) {
      float o = fmaxf(__builtin_fmaf(acc[j], inv, 0.f) + par[P_BIAS1 + chbase + j], 0.f);
      ob[j] = (bf16)o;
    }
    *(uint4*)(hout + (size_t)dst * F1 + chbase) = *(uint4*)ob;
  }
}

// ---------------- layer-2 aggregation ----------------
__global__ __launch_bounds__(256) void agg2_k(
    const bf16* __restrict__ xl2, const bf16* __restrict__ xr2,
    const float* __restrict__ par,
    const int* __restrict__ offs, const int* __restrict__ csr,
    bf16* __restrict__ h2) {
  const int dst = blockIdx.x * 4 + (threadIdx.x >> 6);
  if (dst >= N_NODES) return;
  const int lane = threadIdx.x & 63;
  const int g = lane >> 3;
  const int sl = lane & 7;
  const int chb = sl * 16;

  float r[16], a[16];
  load8bf(xr2 + (size_t)dst * F2 + chb, r);
  load8bf(xr2 + (size_t)dst * F2 + chb + 8, r + 8);
#pragma unroll
  for (int j = 0; j < 16; j += 4) {
    float4 av = *(const float4*)(par + P_ATT2 + chb + j);
    a[j]=av.x; a[j+1]=av.y; a[j+2]=av.z; a[j+3]=av.w;
  }

  const int e0 = offs[dst], e1 = offs[dst + 1];
  float acc[16];
#pragma unroll
  for (int j = 0; j < 16; j++) acc[j] = 0.f;
  float denom = 0.f;

  for (int base = e0; base < e1; base += 8) {
    int e = base + g;
    float v[16], lt;
    if (e < e1) {
      int src = csr[e];
      load8bf(xl2 + (size_t)src * F2 + chb, v);
      load8bf(xl2 + (size_t)src * F2 + chb + 8, v + 8);
      lt = 0.f;
#pragma unroll
      for (int j = 0; j < 16; j++)
        lt = __builtin_fmaf(lrelu(v[j] + r[j]), a[j], lt);
    } else {
#pragma unroll
      for (int j = 0; j < 16; j++) v[j] = 0.f;
      lt = -1e30f;
    }
    lt += __shfl_xor(lt, 1, 64);
    lt += __shfl_xor(lt, 2, 64);
    lt += __shfl_xor(lt, 4, 64);
    float p = __expf(fminf(lt, 60.f));
    denom += p;
#pragma unroll
    for (int j = 0; j < 16; j++) acc[j] = __builtin_fmaf(p, v[j], acc[j]);
  }

#pragma unroll
  for (int m = 8; m <= 32; m <<= 1) {
    denom += __shfl_xor(denom, m, 64);
#pragma unroll
    for (int j = 0; j < 16; j++) acc[j] += __shfl_xor(acc[j], m, 64);
  }

  if (g == 0) {
    float inv = 1.f / (denom + EPS_A);
    __align__(16) bf16 ob[16];
#pragma unroll
    for (int j = 0; j < 16; j++) {
      float o = fmaxf(acc[j] * inv + par[P_BIAS2 + chb + j], 0.f);
      ob[j] = (bf16)o;
    }
    *(uint4*)(h2 + (size_t)dst * F2 + chb)     = *(uint4*)ob;
    *(uint4*)(h2 + (size_t)dst * F2 + chb + 8) = *(uint4*)(ob + 8);
  }
}

// ---------------- pooling (batch is sorted) ----------------
__global__ void binit_k(int* __restrict__ gs, int* __restrict__ ge) {
  int g = threadIdx.x;
  if (g < NGRAPH) { gs[g] = INT_MAX; ge[g] = -1; }
}

// batch sorted -> graph boundaries are local transitions. No atomics.
__global__ void bounds_k(const int* __restrict__ batch,
                         int* __restrict__ gs, int* __restrict__ ge) {
  int n = blockIdx.x * 256 + threadIdx.x;
  if (n >= N_NODES) return;
  int b = batch[n];
  if (n == 0) {
    gs[b] = 0;
  } else {
    int bp = batch[n - 1];
    if (bp != b) { gs[b] = n; ge[bp] = n - 1; }
  }
  if (n == N_NODES - 1) ge[b] = N_NODES - 1;
}

__global__ __launch_bounds__(256) void pool_k(
    const bf16* __restrict__ h2, const int* __restrict__ gs,
    const int* __restrict__ ge, const int* __restrict__ flag,
    void* __restrict__ out) {
  const int g = blockIdx.x;
  const int t = threadIdx.x;
  const int c = t & 127, half = t >> 7;
  const int s = gs[g], e = ge[g];
  float sum = 0.f;
  for (int n = s + half; n <= e; n += 2)
    sum += (float)h2[(size_t)n * F2 + c];
  __shared__ float red[128];
  if (half == 1) red[c] = sum;
  __syncthreads();
  if (half == 0) {
    float tot = sum + red[c];
    float cnt = (e >= s) ? (float)(e - s + 1) : 1.f;
    float v = tot / cnt;
    if (*flag) ((float*)out)[g * F2 + c] = v;
    else       ((bf16*)out)[g * F2 + c] = (bf16)v;
  }
}

// ---------------- launch ----------------
extern "C" void kernel_launch(void* const* d_in, const int* in_sizes, int n_in,
                              void* d_out, int out_size, void* d_ws, size_t ws_size,
                              hipStream_t stream) {
  (void)in_sizes; (void)n_in; (void)out_size; (void)ws_size;
  const void* x     = d_in[0];
  const int*  ei    = (const int*)d_in[1];
  const int*  batch = (const int*)d_in[2];

  char* ws = (char*)d_ws;
  int*   flag = (int*)(ws + OFF_FLAG);
  float* par  = (float*)(ws + OFF_PAR);
  bf16* xl1 = (bf16*)(ws + OFF_XL1);
  bf16* xr1 = (bf16*)(ws + OFF_XR1);
  bf16* h   = (bf16*)(ws + OFF_H);
  bf16* xl2 = (bf16*)(ws + OFF_XL2);
  bf16* xr2 = (bf16*)(ws + OFF_XR2);
  bf16* h2  = (bf16*)(ws + OFF_H2);
  bf16* xb  = (bf16*)(ws + OFF_XB);
  bf16* wt1 = (bf16*)(ws + OFF_WT1);
  bf16* wt2 = (bf16*)(ws + OFF_WT2);
  int* cnt    = (int*)(ws + OFF_CNT);
  int* offs   = (int*)(ws + OFF_OFFS);
  int* cursor = (int*)(ws + OFF_CUR);
  int* csr    = (int*)(ws + OFF_CSR);
  int* gs     = (int*)(ws + OFF_GS);
  int* ge     = (int*)(ws + OFF_GE);

  hipMemsetAsync(cnt, 0, (size_t)N_NODES * 4, stream);

  detect_k<<<1, 64, 0, stream>>>(x, flag);

  CvtArgs ca;
  const int srcidx[12] = {3, 4, 5, 6, 7, 8, 9, 10, 11, 12, 13, 14};
  const int ns[12]     = {IN_F * F1, F1, IN_F * F1, F1, F1, F1,
                          F1 * F2, F2, F1 * F2, F2, F2, F2};
  const int doff[12]   = {P_WL1, P_BL1, P_WR1, P_BR1, P_ATT1, P_BIAS1,
                          P_WL2, P_BL2, P_WR2, P_BR2, P_ATT2, P_BIAS2};
  for (int i = 0; i < 12; i++) { ca.src[i] = d_in[srcidx[i]]; ca.n[i] = ns[i]; ca.dstoff[i] = doff[i]; }
  convert_k<<<dim3((F1 * F2 + 255) / 256, 12), 256, 0, stream>>>(ca, flag, par);

  xprep_k<<<(N_NODES * 64 + 255) / 256, 256, 0, stream>>>(flag, x, xb);
  wprep1_k<<<(512 * 64 + 255) / 256, 256, 0, stream>>>(flag, d_in[3], d_in[5], wt1);
  wprep2_k<<<(256 * 256 + 255) / 256, 256, 0, stream>>>(flag, d_in[9], d_in[11], wt2);

  const int ebl = (TOT_E + 255) / 256;
  const int gblk = (N_NODES + 31) / 32;   // 1563

  gemm1_mfma_k<<<gblk, 256, 0, stream>>>(xb, wt1, par, xl1, xr1);
  count_k<<<ebl, 256, 0, stream>>>(ei, cnt);
  scan_k<<<1, 1024, 0, stream>>>(cnt, offs, cursor);
  scatter_k<<<ebl, 256, 0, stream>>>(ei, cursor, csr);
  binit_k<<<1, 128, 0, stream>>>(gs, ge);
  bounds_k<<<(N_NODES + 255) / 256, 256, 0, stream>>>(batch, gs, ge);
  agg1_k<<<N_NODES, 256, 0, stream>>>(xl1, xr1, par, offs, csr, h);
  gemm2_mfma_k<<<gblk, 256, 0, stream>>>(h, wt2, par, xl2, xr2);
  agg2_k<<<(N_NODES + 3) / 4, 256, 0, stream>>>(xl2, xr2, par, offs, csr, h2);
  pool_k<<<NGRAPH, 256, 0, stream>>>(h2, gs, ge, flag, d_out);
}